// Round 2
// baseline (91.492 us; speedup 1.0000x reference)
//
#include <hip/hip_runtime.h>

#define NITERS 200

// v + (v shuffled per DPP ctrl). CTRL compile-time; all 64 lanes active.
template<int CTRL>
__device__ __forceinline__ float dpp_add(float v) {
    int y = __builtin_amdgcn_mov_dpp(__float_as_int(v), CTRL, 0xF, 0xF, true);
    return v + __int_as_float(y);
}

// xor16 / xor32 butterfly adds. gfx950 permlane*_swap (VALU latency) when
// available; ds_bpermute-based __shfl_xor fallback otherwise.
#if __has_builtin(__builtin_amdgcn_permlane16_swap)
__device__ __forceinline__ float xor16_add(float v) {
    unsigned u = __float_as_uint(v);
    auto r = __builtin_amdgcn_permlane16_swap(u, u, false, false);
    return __uint_as_float(r[0]) + __uint_as_float(r[1]);
}
#else
__device__ __forceinline__ float xor16_add(float v) { return v + __shfl_xor(v, 16, 64); }
#endif

#if __has_builtin(__builtin_amdgcn_permlane32_swap)
__device__ __forceinline__ float xor32_add(float v) {
    unsigned u = __float_as_uint(v);
    auto r = __builtin_amdgcn_permlane32_swap(u, u, false, false);
    return __uint_as_float(r[0]) + __uint_as_float(r[1]);
}
#else
__device__ __forceinline__ float xor32_add(float v) { return v + __shfl_xor(v, 32, 64); }
#endif

__global__ __launch_bounds__(64)
void sinkhorn64x8(const float* __restrict__ theta,
                  const float* __restrict__ phi,
                  const float* __restrict__ trH,
                  const float* __restrict__ wmax,
                  const float* __restrict__ a,
                  float* __restrict__ out)
{
    const int lane = threadIdx.x & 63;
    const int j = lane & 7;    // column owned by this lane
    const int r = lane >> 3;   // row-group (8 rows per lane)
    const int l0 = r * 8;

    // denom = 2^bits - 1, bits = {2..8,16}
    const float denomj = (j == 7) ? 65535.0f : (float)((1u << (j + 2)) - 1u);
    const float inv_den = 1.0f / denomj;

    // b = softmax(phi) (max-subtracted, matching jax.nn.softmax); B = b[j] + 1e-40
    float ph[8];
#pragma unroll
    for (int k = 0; k < 8; ++k) ph[k] = phi[k];
    float mx = ph[0];
#pragma unroll
    for (int k = 1; k < 8; ++k) mx = fmaxf(mx, ph[k]);
    float es = 0.0f, ee[8];
#pragma unroll
    for (int k = 0; k < 8; ++k) { ee[k] = expf(ph[k] - mx); es += ee[k]; }
    const float B = ee[j] / es + 1e-40f;

    // Per-row constants: E[i] = exp(K[l][j]); EA[i] = E[i] * (a[l]+1e-40)
    float E[8], EA[8];
#pragma unroll
    for (int i = 0; i < 8; ++i) {
        const int l = l0 + i;
        const float w = wmax[l];
        const float d = 2.0f * w * inv_den;
        const float C = 0.5f * trH[l] * (d * d * (1.0f / 12.0f));
        const float K = (theta[l * 8 + j] - C) / 0.02f;   // -(C - theta)/EPS
        E[i] = expf(K);
        EA[i] = E[i] * (a[l] + 1e-40f);
    }

    // Multiplicative Sinkhorn: F = A/(E G), G = B/(E^T F); F=G=1 <=> f=g=0.
    // rinv[i] = 1/p[i] carries F implicitly: F[i] = A[i]*rinv[i].
    float rinv[8];
    float G = 1.0f;

#pragma unroll 2
    for (int it = 0; it < NITERS; ++it) {
        // --- row update: p_l = sum_j E[l][j]*G_j (butterfly over 8 lanes) ---
        float p[8];
#pragma unroll
        for (int i = 0; i < 8; ++i) p[i] = E[i] * G;
#pragma unroll
        for (int i = 0; i < 8; ++i) {
            p[i] = dpp_add<0xB1>(p[i]);   // xor 1  (quad_perm [1,0,3,2])
            p[i] = dpp_add<0x4E>(p[i]);   // xor 2  (quad_perm [2,3,0,1])
            p[i] = dpp_add<0x141>(p[i]);  // xor 4  (row_half_mirror)
        }
#pragma unroll
        for (int i = 0; i < 8; ++i) rinv[i] = __builtin_amdgcn_rcpf(p[i]);

        // --- col update: S_j = sum_l E[l][j]*A_l/p_l = sum_i EA[i]*rinv[i] ---
        const float q01 = EA[0] * rinv[0] + EA[1] * rinv[1];
        const float q23 = EA[2] * rinv[2] + EA[3] * rinv[3];
        const float q45 = EA[4] * rinv[4] + EA[5] * rinv[5];
        const float q67 = EA[6] * rinv[6] + EA[7] * rinv[7];
        float q = (q01 + q23) + (q45 + q67);
        q = dpp_add<0x128>(q);            // xor 8  (row_ror:8)
        q = xor16_add(q);                 // xor 16 (permlane16_swap)
        q = xor32_add(q);                 // xor 32 (permlane32_swap)
        G = B * __builtin_amdgcn_rcpf(q);
    }

    // P = E*F*G = EA*rinv*G; out = P / (P.sum() + 1e-40)
    float P[8];
#pragma unroll
    for (int i = 0; i < 8; ++i) P[i] = EA[i] * rinv[i] * G;
    float t = ((P[0] + P[1]) + (P[2] + P[3])) + ((P[4] + P[5]) + (P[6] + P[7]));
    t = dpp_add<0xB1>(t);
    t = dpp_add<0x4E>(t);
    t = dpp_add<0x141>(t);
    t = dpp_add<0x128>(t);
    t = xor16_add(t);
    t = xor32_add(t);
    const float inv = 1.0f / (t + 1e-40f);
#pragma unroll
    for (int i = 0; i < 8; ++i) out[(l0 + i) * 8 + j] = P[i] * inv;
}

extern "C" void kernel_launch(void* const* d_in, const int* in_sizes, int n_in,
                              void* d_out, int out_size, void* d_ws, size_t ws_size,
                              hipStream_t stream) {
    const float* theta = (const float*)d_in[0];
    const float* phi   = (const float*)d_in[1];
    const float* trH   = (const float*)d_in[2];
    const float* wmax  = (const float*)d_in[3];
    const float* a     = (const float*)d_in[4];
    float* out = (float*)d_out;
    sinkhorn64x8<<<dim3(1), dim3(64), 0, stream>>>(theta, phi, trH, wmax, a, out);
}

// Round 8
// 82.662 us; speedup vs baseline: 1.1068x; 1.1068x over previous
//
#include <hip/hip_runtime.h>

#define NITERS 200

// Plain DPP move (cross-lane), CTRL compile-time, all lanes valid.
template<int CTRL>
__device__ __forceinline__ float dpp_mov(float v) {
    return __int_as_float(
        __builtin_amdgcn_mov_dpp(__float_as_int(v), CTRL, 0xF, 0xF, true));
}
// a + dpp(b) — fusable into v_add_f32_dpp by GCNDPPCombine.
template<int CTRL>
__device__ __forceinline__ float dpp_add(float a, float b) {
    return a + dpp_mov<CTRL>(b);
}

// DPP controls. NOTE (round-7 bug fix): 0x141 row_half_mirror is j -> 7-j
// (= j^7 within each 8-lane half-row), NOT j^4. Full reductions tolerate it
// (quad-uniform inputs); the pruned twisted butterfly must pair via masks
// {1, 2, 7} so the mirror level is algebraically exact.
#define XOR1 0xB1   // quad_perm [1,0,3,2]  : lane j -> j^1
#define XOR2 0x4E   // quad_perm [2,3,0,1]  : lane j -> j^2
#define MIR7 0x141  // row_half_mirror      : lane j -> j^7 (within 8)
#define XOR8 0x128  // row_ror:8            : lane j -> j^8 (within 16)

// xor16 / xor32 butterfly adds via gfx950 permlane*_swap (VALU latency).
#if __has_builtin(__builtin_amdgcn_permlane16_swap)
__device__ __forceinline__ float xor16_add(float v) {
    unsigned u = __float_as_uint(v);
    auto r = __builtin_amdgcn_permlane16_swap(u, u, false, false);
    return __uint_as_float(r[0]) + __uint_as_float(r[1]);
}
#else
__device__ __forceinline__ float xor16_add(float v) { return v + __shfl_xor(v, 16, 64); }
#endif
#if __has_builtin(__builtin_amdgcn_permlane32_swap)
__device__ __forceinline__ float xor32_add(float v) {
    unsigned u = __float_as_uint(v);
    auto r = __builtin_amdgcn_permlane32_swap(u, u, false, false);
    return __uint_as_float(r[0]) + __uint_as_float(r[1]);
}
#else
__device__ __forceinline__ float xor32_add(float v) { return v + __shfl_xor(v, 32, 64); }
#endif

__global__ __launch_bounds__(64)
void sinkhorn64x8(const float* __restrict__ theta,
                  const float* __restrict__ phi,
                  const float* __restrict__ trH,
                  const float* __restrict__ wmax,
                  const float* __restrict__ a,
                  float* __restrict__ out)
{
    const int lane = threadIdx.x & 63;
    const int j = lane & 7;    // column owned by this lane
    const int r = lane >> 3;   // row-group (8 rows per group)
    const int l0 = r * 8;

    // denom = 2^bits - 1, bits = {2..8,16}
    const float denomj = (j == 7) ? 65535.0f : (float)((1u << (j + 2)) - 1u);
    const float inv_den = 1.0f / denomj;

    // b = softmax(phi) (max-subtracted); B = b[j] + 1e-40
    float ph[8];
#pragma unroll
    for (int k = 0; k < 8; ++k) ph[k] = phi[k];
    float mx = ph[0];
#pragma unroll
    for (int k = 1; k < 8; ++k) mx = fmaxf(mx, ph[k]);
    float es = 0.0f, ee[8];
#pragma unroll
    for (int k = 0; k < 8; ++k) { ee[k] = expf(ph[k] - mx); es += ee[k]; }
    const float B = ee[j] / es + 1e-40f;

    // TWISTED layout: slot i of lane (r,j) holds row l = l0 + (j^i), column j.
    // E[i] = exp(K[l][j]);  EA[i] = E[i] * (a[l]+1e-40)
    float E[8], EA[8];
#pragma unroll
    for (int i = 0; i < 8; ++i) {
        const int l = l0 + (j ^ i);
        const float w = wmax[l];
        const float d = 2.0f * w * inv_den;
        const float C = 0.5f * trH[l] * (d * d * (1.0f / 12.0f));
        const float K = (theta[l * 8 + j] - C) / 0.02f;   // -(C - theta)/EPS
        E[i] = expf(K);
        EA[i] = E[i] * (a[l] + 1e-40f);
    }

    // Multiplicative Sinkhorn: F = A/(E G), G = B/(E^T F); F=G=1 <=> f=g=0.
    // rv[i] = 1/rowsum(row l0+(j^i)) carries F implicitly: F = A*rv.
    float rv[8];
#pragma unroll
    for (int i = 0; i < 8; ++i) rv[i] = 0.0f;  // init (overwritten in loop)
    float G = 1.0f;

    for (int it = 0; it < NITERS; ++it) {
        // --- row phase: products x[i] = E[i]*G (row l0+(j^i), col j) ---
        float x0 = E[0] * G, x1 = E[1] * G, x2 = E[2] * G, x3 = E[3] * G;
        float x4 = E[4] * G, x5 = E[5] * G, x6 = E[6] * G, x7 = E[7] * G;
        // Pruned twisted butterfly with level masks {1, 2, 7}:
        // L1 pairs slots (0,1),(2,3),(5,4),(7,6); L2 pairs (0,2),(7,5);
        // L3 pairs (0,7) via the mirror (lane j^7, row (j^7)^7 = j). Exact.
        const float s0 = dpp_add<XOR1>(x0, x1);  // row j,   cols {j,j^1}
        const float s2 = dpp_add<XOR1>(x2, x3);  // row j^2, cols {j,j^1}
        const float s5 = dpp_add<XOR1>(x5, x4);  // row j^5, cols {j,j^1}
        const float s7 = dpp_add<XOR1>(x7, x6);  // row j^7, cols {j,j^1}
        const float t0 = dpp_add<XOR2>(s0, s2);  // row j,   cols {j..j^3}
        const float t7 = dpp_add<XOR2>(s7, s5);  // row j^7, cols {j..j^3}
        const float p  = dpp_add<MIR7>(t0, t7);  // row j,   all 8 cols
        const float rinv = __builtin_amdgcn_rcpf(p);  // ONE rcp for all 64 rows

        // Allgather: rv[s] = rinv of row l0+(j^s).
        rv[0] = rinv;
        rv[1] = dpp_mov<XOR1>(rv[0]);
        rv[2] = dpp_mov<XOR2>(rv[0]);
        rv[3] = dpp_mov<XOR2>(rv[1]);
        rv[7] = dpp_mov<MIR7>(rv[0]);   // lane j^7 -> row j^7
        rv[6] = dpp_mov<MIR7>(rv[1]);   // row (j^7)^1 = j^6
        rv[5] = dpp_mov<MIR7>(rv[2]);   // row j^5
        rv[4] = dpp_mov<MIR7>(rv[3]);   // row j^4

        // --- col phase: S_j = sum_l E[l][j]*A_l/p_l = sum_i EA[i]*rv[i] ---
        const float q01 = EA[0] * rv[0] + EA[1] * rv[1];
        const float q23 = EA[2] * rv[2] + EA[3] * rv[3];
        const float q45 = EA[4] * rv[4] + EA[5] * rv[5];
        const float q67 = EA[6] * rv[6] + EA[7] * rv[7];
        float q = (q01 + q23) + (q45 + q67);
        q = dpp_add<XOR8>(q, q);          // xor 8 (exact: ror8 = j^8)
        q = xor16_add(q);                 // xor 16
        q = xor32_add(q);                 // xor 32
        G = B * __builtin_amdgcn_rcpf(q);
    }

    // P[i] = E*F*G = EA[i]*rv[i]*G ; out = P / (P.sum() + 1e-40)
    float P[8];
#pragma unroll
    for (int i = 0; i < 8; ++i) P[i] = EA[i] * rv[i] * G;
    float t = ((P[0] + P[1]) + (P[2] + P[3])) + ((P[4] + P[5]) + (P[6] + P[7]));
    // Full 64-lane reduction: mirror is safe here (quad-uniform after xor1+xor2).
    t = dpp_add<XOR1>(t, t);
    t = dpp_add<XOR2>(t, t);
    t = dpp_add<MIR7>(t, t);
    t = dpp_add<XOR8>(t, t);
    t = xor16_add(t);
    t = xor32_add(t);
    const float inv = 1.0f / (t + 1e-40f);
#pragma unroll
    for (int i = 0; i < 8; ++i)
        out[(l0 + (j ^ i)) * 8 + j] = P[i] * inv;
}

extern "C" void kernel_launch(void* const* d_in, const int* in_sizes, int n_in,
                              void* d_out, int out_size, void* d_ws, size_t ws_size,
                              hipStream_t stream) {
    const float* theta = (const float*)d_in[0];
    const float* phi   = (const float*)d_in[1];
    const float* trH   = (const float*)d_in[2];
    const float* wmax  = (const float*)d_in[3];
    const float* a     = (const float*)d_in[4];
    float* out = (float*)d_out;
    sinkhorn64x8<<<dim3(1), dim3(64), 0, stream>>>(theta, phi, trH, wmax, a, out);
}